// Round 14
// baseline (1387.750 us; speedup 1.0000x reference)
//
#include <hip/hip_runtime.h>

typedef __attribute__((ext_vector_type(8))) short bf16x8;
typedef __attribute__((ext_vector_type(4))) short bf16x4;
typedef __attribute__((ext_vector_type(4))) float f32x4;

__device__ __forceinline__ short f2bf(float f) {
  union { float f; unsigned u; } v; v.f = f;
  unsigned r = v.u + 0x7fffu + ((v.u >> 16) & 1u);
  return (short)(r >> 16);
}
__device__ __forceinline__ float sigm(float x) {
  float e = exp2f(-1.44269504f * x);
  return __builtin_amdgcn_rcpf(1.0f + e);
}
__device__ __forceinline__ float tanh_f(float x) {
  float e = exp2f(-2.88539008f * x);          // tanh(x) = 2*sigm(2x)-1, overflow-free
  return __builtin_fmaf(2.0f, __builtin_amdgcn_rcpf(1.0f + e), -1.0f);
}
__device__ __forceinline__ f32x4 splat4(float b){ f32x4 v = {b,b,b,b}; return v; }

// L1-bypassing 16B load (agent-coherent, reads L2 directly). In this kernel
// every issue burst is drained by vmcnt(0) BEFORE leaving the enclosing
// statement region — no asm-written register is live-but-undefined across an
// iteration boundary (R13 post-mortem: regalloc may copy/spill asm dests).
__device__ __forceinline__ void ld_b128_sc0(bf16x8* d, const void* p) {
  asm volatile("global_load_dwordx4 %0, %1, off sc0" : "=&v"(*d) : "v"(p));
}
__device__ __forceinline__ void vm_drain_sched() {
  asm volatile("s_waitcnt vmcnt(0)" ::: "memory");
  __builtin_amdgcn_sched_barrier(0);
}

// ws layout (shorts for wp):
//  R1  [16 mem][4 g][8 kc][64 l][8 e]   W_hh1, gate-per-acc packing (512KB)
//  R2a [16][2 gh][8 kc][64][8]          W_ih2, gate-pair packing    (256KB)
//  R2b [16][2][4][64][8]                W_hh2, gate-pair packing    (128KB)
//  R1i [16][4 g][8][64][8]              W_ih1, gate-per-acc packing (512KB)
#define R1S   0
#define R2AS  262144
#define R2BS  393216
#define R1IS  458752
#define CTRL_B 1441792   // claim[xcd] @ dword xcd*32 ; flags[g] @ dword 512+g*64
// exchange, slab-major: h0 [2 slot][16 grp][16 slab=member][256 row][16 u *2B]
#define H0X_B  1462272   // = 4MB
// h1 [2 slot][16 grp][16 slab=member][256 row][8 u *2B]
#define H1X_B  5656576   // = 2MB

// LDS byte offsets (weights 0..57343)
#define H0S 57344        // stage [256 row][16 u] bf16 = 8KB
#define H1S 65536        // stage [256 row][8 u]  bf16 = 4KB
#define OUTS 69632       // stage [256 row][8 u]  f32  = 8KB

__global__ __launch_bounds__(256) void pack_w(
    const float* __restrict__ W_ih1, const float* __restrict__ W_hh1,
    const float* __restrict__ W_ih2, const float* __restrict__ W_hh2,
    short* __restrict__ wp) {
  int s = blockIdx.x * 256 + threadIdx.x;
  if (blockIdx.x == 0) {   // zero 20KB control region each launch
    unsigned* c = (unsigned*)((char*)wp + CTRL_B);
    #pragma unroll
    for (int k = 0; k < 20; ++k) c[threadIdx.x + k * 256] = 0u;
  }
  if (s >= 90112) return;
  const float* src; int row, K, k0, l;
  if (s < 32768) {            // R1 <- W_hh1 [1024][256], gate-per-acc: col = l&15
    int mm = s >> 11, r = s & 2047, g = r >> 9, kc = (r >> 6) & 7; l = r & 63;
    row = g*256 + mm*16 + (l & 15); K = 256; k0 = kc*32 + (l>>4)*8; src = W_hh1;
  } else if (s < 49152) {     // R2a <- W_ih2 [512][256], gate-pair (unchanged)
    int s2 = s - 32768, mm = s2 >> 10, r = s2 & 1023, gh = r >> 9, kc = (r >> 6) & 7; l = r & 63;
    int ul = (l & 15) >> 1, gp = l & 1;
    row = (gh*2+gp)*128 + mm*8 + ul; K = 256; k0 = kc*32 + (l>>4)*8; src = W_ih2;
  } else if (s < 57344) {     // R2b <- W_hh2 [512][128], gate-pair (unchanged)
    int s3 = s - 49152, mm = s3 >> 9, r = s3 & 511, gh = r >> 8, kc = (r >> 6) & 3; l = r & 63;
    int ul = (l & 15) >> 1, gp = l & 1;
    row = (gh*2+gp)*128 + mm*8 + ul; K = 128; k0 = kc*32 + (l>>4)*8; src = W_hh2;
  } else {                    // R1i <- W_ih1 [1024][256], gate-per-acc: col = l&15
    int s4 = s - 57344, mm = s4 >> 11, r = s4 & 2047, g = r >> 9, kc = (r >> 6) & 7; l = r & 63;
    row = g*256 + mm*16 + (l & 15); K = 256; k0 = kc*32 + (l>>4)*8; src = W_ih1;
  }
  const float* p = src + (size_t)row * K + k0;
  bf16x8 o;
  #pragma unroll
  for (int e = 0; e < 8; ++e) o[e] = f2bf(p[e]);
  *(bf16x8*)(wp + (size_t)s * 8) = o;
}

// 256 blocks x 512 threads, 1 block/CU. 16 groups x 16 members, 256 rows/group.
// R12 structure with ONE barrier per iteration: h0(u)+h1(u-1) publish together
// under a single drain+sync+flag (flag=u+1 => both visible). Exchange loads
// issue after the poll and are drained IMMEDIATELY (no in-flight asm regs
// across the iteration boundary — R13 lesson). out NT store drains with them.
__global__ __launch_bounds__(512, 2) void lstm_persist(
    const float* __restrict__ emb, const float* __restrict__ b_ih1,
    const float* __restrict__ b_hh1, const float* __restrict__ b_ih2,
    const float* __restrict__ b_hh2, char* __restrict__ ws,
    float* __restrict__ out) {
  extern __shared__ __align__(16) short ldsW[];
  char* ldsB = (char*)ldsW;
  const short* wp = (const short*)ws;
  unsigned* ctrl = (unsigned*)(ws + CTRL_B);
  __shared__ unsigned s_gm;
  const int tid = threadIdx.x, w = tid >> 6, l = tid & 63, l15 = l & 15, l4 = l >> 4;
  const int ul = l15 >> 1, gp = l15 & 1;

  // claim a (group, member) slot on this block's own XCD -> same-XCD groups
  if (tid == 0) {
    unsigned xcc;
    asm volatile("s_getreg_b32 %0, hwreg(HW_REG_XCC_ID)" : "=s"(xcc));
    xcc &= 7u;
    unsigned slot = atomicAdd(&ctrl[xcc * 32], 1u);
    s_gm = ((xcc * 2u + ((slot >> 4) & 1u)) << 8) | (slot & 15u);
  }
  __syncthreads();
  const int group = s_gm >> 8, member = s_gm & 255;

  // copy this member's weight slices into LDS (56KB: W_hh1 32KB | W_ih2 16KB | W_hh2 8KB)
  {
    const char* wpB = (const char*)wp;
    #pragma unroll
    for (int it = 0; it < 7; ++it) {
      int byte = (tid + it * 512) * 16;
      const char* src;
      if (byte < 32768)      src = wpB + (size_t)R1S * 2  + member * 32768 + byte;
      else if (byte < 49152) src = wpB + (size_t)R2AS * 2 + member * 16384 + (byte - 32768);
      else                   src = wpB + (size_t)R2BS * 2 + member * 8192  + (byte - 49152);
      *(f32x4*)(ldsB + byte) = *(const f32x4*)src;
    }
  }
  float b2[2];
  #pragma unroll
  for (int gh = 0; gh < 2; ++gh) {
    int rw = (gh*2+gp)*128 + member*8 + ul;
    b2[gh] = b_ih2[rw] + b_hh2[rw];
  }
  float b1[4];
  #pragma unroll
  for (int g = 0; g < 4; ++g) {
    int rw = g*256 + member*16 + l15;
    b1[g] = b_ih1[rw] + b_hh1[rw];
  }
  __syncthreads();   // LDS weights ready

  // x1 = emb @ W_ih1^T + b1 for rows [group*256 + w*32, +32), kept in registers
  const int grow0 = group * 256;
  const int rw0 = w * 32;
  f32x4 x1[2][4];
  #pragma unroll
  for (int m = 0; m < 2; ++m)
    #pragma unroll
    for (int g = 0; g < 4; ++g) x1[m][g] = splat4(b1[g]);
  #pragma unroll
  for (int kc = 0; kc < 8; ++kc) {
    bf16x8 af[2];
    #pragma unroll
    for (int m = 0; m < 2; ++m) {
      const float* ep = emb + (size_t)(grow0 + rw0 + m*16 + l15) * 256 + kc*32 + l4*8;
      f32x4 lo = *(const f32x4*)ep, hi = *(const f32x4*)(ep + 4);
      bf16x8 t8;
      #pragma unroll
      for (int e = 0; e < 4; ++e) { t8[e] = f2bf(lo[e]); t8[e+4] = f2bf(hi[e]); }
      af[m] = t8;
    }
    #pragma unroll
    for (int g = 0; g < 4; ++g) {
      bf16x8 bb = *(const bf16x8*)(wp + R1IS + (((size_t)member*4 + g)*8 + kc)*512 + l*8);
      x1[0][g] = __builtin_amdgcn_mfma_f32_16x16x32_bf16(af[0], bb, x1[0][g], 0, 0, 0);
      x1[1][g] = __builtin_amdgcn_mfma_f32_16x16x32_bf16(af[1], bb, x1[1][g], 0, 0, 0);
    }
  }

  bf16x8 a0[2][8], a1[2][4];
  const bf16x8 ZB = {0,0,0,0,0,0,0,0};
  #pragma unroll
  for (int m = 0; m < 2; ++m) {
    #pragma unroll
    for (int kc = 0; kc < 8; ++kc) a0[m][kc] = ZB;
    #pragma unroll
    for (int kc = 0; kc < 4; ++kc) a1[m][kc] = ZB;
  }
  float c0[2][4] = {};   // [m][r] — register-local layer1 gates
  float c1[2][2] = {};   // [m][rr]

  unsigned* flg = &ctrl[512 + group * 64];        // 16 words, own 128B line
  char* h0x = ws + H0X_B;
  char* h1x = ws + H1X_B;

  #pragma unroll 1
  for (int u = 0; u <= 128; ++u) {
    // ============ layer1(u): MFMA + register-local gates1 + stage/publish h0 ====
    if (u < 128) {
      f32x4 acc1[2][4];
      #pragma unroll
      for (int m = 0; m < 2; ++m)
        #pragma unroll
        for (int g = 0; g < 4; ++g) acc1[m][g] = x1[m][g];
      #pragma unroll
      for (int g = 0; g < 4; ++g)
        #pragma unroll
        for (int kc = 0; kc < 8; ++kc) {
          bf16x8 bb = *(const bf16x8*)(ldsW + (g*8 + kc)*512 + l*8);
          acc1[0][g] = __builtin_amdgcn_mfma_f32_16x16x32_bf16(a0[0][kc], bb, acc1[0][g], 0,0,0);
          acc1[1][g] = __builtin_amdgcn_mfma_f32_16x16x32_bf16(a0[1][kc], bb, acc1[1][g], 0,0,0);
        }
      #pragma unroll
      for (int m = 0; m < 2; ++m)
        #pragma unroll
        for (int r = 0; r < 4; ++r) {
          float iv = acc1[m][0][r], fv = acc1[m][1][r];
          float gv = acc1[m][2][r], ov = acc1[m][3][r];
          float c = sigm(fv) * c0[m][r] + sigm(iv) * tanh_f(gv);
          c0[m][r] = c;
          float h = sigm(ov) * tanh_f(c);
          int row = rw0 + m*16 + l4*4 + r;
          *(short*)(ldsB + H0S + row*32 + l15*2) = f2bf(h);
        }
      // coalesced publish h0: my wave's 32-row window = one dwordx4 per lane
      {
        char* h0w = h0x + ((size_t)(u & 1) * 16 + group) * 131072;
        int prow = rw0 + (l >> 1);
        int off = prow*32 + (l & 1)*16;
        bf16x8 v = *(const bf16x8*)(ldsB + H0S + off);
        *(bf16x8*)(h0w + member*8192 + off) = v;
      }
      // (drains at the single barrier below, together with h1)
    }
    // ============ layer2(u-1): MFMA + gates2 + stage h1/OUTS + publish h1 ========
    if (u >= 1) {
      const int t = u - 1;
      f32x4 acc2[2][2];
      #pragma unroll
      for (int m = 0; m < 2; ++m)
        #pragma unroll
        for (int gh = 0; gh < 2; ++gh) acc2[m][gh] = splat4(b2[gh]);
      #pragma unroll
      for (int gh = 0; gh < 2; ++gh)
        #pragma unroll
        for (int kc = 0; kc < 8; ++kc) {
          bf16x8 bb = *(const bf16x8*)(ldsW + 16384 + (gh*8 + kc)*512 + l*8);
          acc2[0][gh] = __builtin_amdgcn_mfma_f32_16x16x32_bf16(a0[0][kc], bb, acc2[0][gh], 0,0,0);
          acc2[1][gh] = __builtin_amdgcn_mfma_f32_16x16x32_bf16(a0[1][kc], bb, acc2[1][gh], 0,0,0);
        }
      #pragma unroll
      for (int gh = 0; gh < 2; ++gh)
        #pragma unroll
        for (int kc = 0; kc < 4; ++kc) {
          bf16x8 bb = *(const bf16x8*)(ldsW + 24576 + (gh*4 + kc)*512 + l*8);
          acc2[0][gh] = __builtin_amdgcn_mfma_f32_16x16x32_bf16(a1[0][kc], bb, acc2[0][gh], 0,0,0);
          acc2[1][gh] = __builtin_amdgcn_mfma_f32_16x16x32_bf16(a1[1][kc], bb, acc2[1][gh], 0,0,0);
        }
      #pragma unroll
      for (int m = 0; m < 2; ++m) {
        f32x4 v0 = acc2[m][0], v1 = acc2[m][1];
        #pragma unroll
        for (int rr = 0; rr < 2; ++rr) {
          float s0 = gp ? v0[rr] : v0[2+rr];
          float s1 = gp ? v1[rr] : v1[2+rr];
          float p0 = __shfl_xor(s0, 1, 64);
          float p1 = __shfl_xor(s1, 1, 64);
          float o0 = gp ? v0[2+rr] : v0[rr];
          float o1 = gp ? v1[2+rr] : v1[rr];
          float iv = gp ? p0 : o0, fv = gp ? o0 : p0;
          float gv = gp ? p1 : o1, ov = gp ? o1 : p1;
          float c = sigm(fv) * c1[m][rr] + sigm(iv) * tanh_f(gv);
          c1[m][rr] = c;
          float h = sigm(ov) * tanh_f(c);
          int row = rw0 + m*16 + l4*4 + gp*2 + rr;
          *(short*)(ldsB + H1S + row*16 + ul*2) = f2bf(h);
          *(float*)(ldsB + OUTS + row*32 + ul*4) = h;
        }
      }
      if (u < 128) {   // h1(127) has no consumer
        char* h1w = h1x + ((size_t)(t & 1) * 16 + group) * 65536;
        int prow = rw0 + (l >> 1);
        int off = prow*16 + (l & 1)*8;
        bf16x4 v = *(const bf16x4*)(ldsB + H1S + off);
        *(bf16x4*)(h1w + member*4096 + off) = v;
      }
    }
    // ============ SINGLE barrier: flag(u+1) = {h0(u), h1(u-1)} visible ============
    if (u < 128) {
      asm volatile("s_waitcnt vmcnt(0)" ::: "memory");   // h0+h1 publishes in L2
      __syncthreads();
      if (tid == 0)
        __hip_atomic_store(&flg[member], (unsigned)(u + 1),
                           __ATOMIC_RELAXED, __HIP_MEMORY_SCOPE_AGENT);
      // out(u-1): coalesced NT store — issued now, drains with the loads below
      if (u >= 1) {
        const int t = u - 1;
        int prow = rw0 + (l >> 1);
        f32x4 v = *(const f32x4*)(ldsB + OUTS + prow*32 + (l & 1)*16);
        float* op = out + (size_t)(grow0 + prow) * 16384 + (size_t)t*128 + member*8 + (l & 1)*4;
        __builtin_nontemporal_store(v, (f32x4*)op);
      }
      // poll: all 16 members published
      {
        unsigned tgt = (unsigned)(u + 1); int z = 0;
        while (true) {
          unsigned v = __hip_atomic_load(&flg[l15], __ATOMIC_RELAXED, __HIP_MEMORY_SCOPE_AGENT);
          if (__all((int)(v >= tgt))) break;
          __builtin_amdgcn_s_sleep(1);
          if (++z > (1 << 20)) break;   // escape hatch: fail visibly, never hang
        }
      }
      __builtin_amdgcn_sched_barrier(0);
      // issue a0 = h0(u), a1 = h1(u-1) loads; drain IMMEDIATELY (R13 lesson:
      // never leave asm-load dests in flight across statement boundaries)
      const char* h0r = h0x + ((size_t)(u & 1) * 16 + group) * 131072;
      #pragma unroll
      for (int m = 0; m < 2; ++m)
        #pragma unroll
        for (int kc = 0; kc < 8; ++kc)
          ld_b128_sc0(&a0[m][kc],
                      h0r + (kc*2 + (l4 >> 1))*8192 + (rw0 + m*16 + l15)*32 + (l4 & 1)*16);
      if (u >= 1) {
        const char* h1r = h1x + ((size_t)((u - 1) & 1) * 16 + group) * 65536;
        #pragma unroll
        for (int m = 0; m < 2; ++m)
          #pragma unroll
          for (int kc = 0; kc < 4; ++kc)
            ld_b128_sc0(&a1[m][kc], h1r + (kc*4 + l4)*4096 + (rw0 + m*16 + l15)*16);
      }
      vm_drain_sched();   // loads valid; out store retired; nothing in flight
    } else {
      // u == 128: final out(127) store
      const int t = 127;
      int prow = rw0 + (l >> 1);
      f32x4 v = *(const f32x4*)(ldsB + OUTS + prow*32 + (l & 1)*16);
      float* op = out + (size_t)(grow0 + prow) * 16384 + (size_t)t*128 + member*8 + (l & 1)*4;
      __builtin_nontemporal_store(v, (f32x4*)op);
    }
  }
}

extern "C" void kernel_launch(void* const* d_in, const int* in_sizes, int n_in,
                              void* d_out, int out_size, void* d_ws, size_t ws_size,
                              hipStream_t stream) {
  const float* emb   = (const float*)d_in[0];
  const float* W_ih1 = (const float*)d_in[1];
  const float* W_hh1 = (const float*)d_in[2];
  const float* b_ih1 = (const float*)d_in[3];
  const float* b_hh1 = (const float*)d_in[4];
  const float* W_ih2 = (const float*)d_in[5];
  const float* W_hh2 = (const float*)d_in[6];
  const float* b_ih2 = (const float*)d_in[7];
  const float* b_hh2 = (const float*)d_in[8];
  char* ws = (char*)d_ws;
  float* out = (float*)d_out;

  hipFuncSetAttribute((const void*)lstm_persist,
                      hipFuncAttributeMaxDynamicSharedMemorySize, 98304);
  pack_w<<<352, 256, 0, stream>>>(W_ih1, W_hh1, W_ih2, W_hh2, (short*)d_ws);
  lstm_persist<<<256, 512, 98304, stream>>>(emb, b_ih1, b_hh1, b_ih2, b_hh2, ws, out);
}

// Round 15
// 872.843 us; speedup vs baseline: 1.5899x; 1.5899x over previous
//
#include <hip/hip_runtime.h>

typedef __attribute__((ext_vector_type(8))) short bf16x8;
typedef __attribute__((ext_vector_type(4))) short bf16x4;
typedef __attribute__((ext_vector_type(4))) float f32x4;

__device__ __forceinline__ short f2bf(float f) {
  union { float f; unsigned u; } v; v.f = f;
  unsigned r = v.u + 0x7fffu + ((v.u >> 16) & 1u);
  return (short)(r >> 16);
}
__device__ __forceinline__ float sigm(float x) {
  float e = exp2f(-1.44269504f * x);
  return __builtin_amdgcn_rcpf(1.0f + e);
}
__device__ __forceinline__ float tanh_f(float x) {
  float e = exp2f(-2.88539008f * x);          // tanh(x) = 2*sigm(2x)-1, overflow-free
  return __builtin_fmaf(2.0f, __builtin_amdgcn_rcpf(1.0f + e), -1.0f);
}
__device__ __forceinline__ f32x4 splat4(float b){ f32x4 v = {b,b,b,b}; return v; }

// L1-bypassing 16B load (agent-coherent, reads L2 directly; value valid only
// after a manual vmcnt drain + sched_barrier — rule #18)
__device__ __forceinline__ void ld_b128_sc0(bf16x8* d, const void* p) {
  asm volatile("global_load_dwordx4 %0, %1, off sc0" : "=&v"(*d) : "v"(p));
}
__device__ __forceinline__ void vm_drain_sched() {
  asm volatile("s_waitcnt vmcnt(0)" ::: "memory");
  __builtin_amdgcn_sched_barrier(0);
}

// ws layout (shorts for wp):
//  R1  [16 mem][4 g][8 kc][64 l][8 e]   W_hh1, gate-per-acc packing (512KB)
//  R2a [16][2 gh][8 kc][64][8]          W_ih2, gate-pair packing    (256KB)
//  R2b [16][2][4][64][8]                W_hh2, gate-pair packing    (128KB)
//  R1i [16][4 g][8][64][8]              W_ih1, gate-per-acc packing (512KB)
#define R1S   0
#define R2AS  262144
#define R2BS  393216
#define R1IS  458752
#define CTRL_B 1441792   // claim[xcd] @ dword xcd*32 ; flagsA[g] @ dword 512+g*64, flagsB @ +32
// exchange, slab-major: h0 [2 slot][16 grp][16 slab=member][256 row][16 u *2B]
#define H0X_B  1462272   // = 4MB
// h1 [2 slot][16 grp][16 slab=member][256 row][8 u *2B]
#define H1X_B  5656576   // = 2MB

// LDS byte offsets (weights 0..57343)
#define H0S 57344        // stage [256 row][16 u] bf16 = 8KB
#define H1S 65536        // stage [256 row][8 u]  bf16 = 4KB
#define OUTS 69632       // stage [256 row][8 u]  f32  = 8KB

__global__ __launch_bounds__(256) void pack_w(
    const float* __restrict__ W_ih1, const float* __restrict__ W_hh1,
    const float* __restrict__ W_ih2, const float* __restrict__ W_hh2,
    short* __restrict__ wp) {
  int s = blockIdx.x * 256 + threadIdx.x;
  if (blockIdx.x == 0) {   // zero 20KB control region each launch
    unsigned* c = (unsigned*)((char*)wp + CTRL_B);
    #pragma unroll
    for (int k = 0; k < 20; ++k) c[threadIdx.x + k * 256] = 0u;
  }
  if (s >= 90112) return;
  const float* src; int row, K, k0, l;
  if (s < 32768) {            // R1 <- W_hh1 [1024][256], gate-per-acc: col = l&15
    int mm = s >> 11, r = s & 2047, g = r >> 9, kc = (r >> 6) & 7; l = r & 63;
    row = g*256 + mm*16 + (l & 15); K = 256; k0 = kc*32 + (l>>4)*8; src = W_hh1;
  } else if (s < 49152) {     // R2a <- W_ih2 [512][256], gate-pair (unchanged)
    int s2 = s - 32768, mm = s2 >> 10, r = s2 & 1023, gh = r >> 9, kc = (r >> 6) & 7; l = r & 63;
    int ul = (l & 15) >> 1, gp = l & 1;
    row = (gh*2+gp)*128 + mm*8 + ul; K = 256; k0 = kc*32 + (l>>4)*8; src = W_ih2;
  } else if (s < 57344) {     // R2b <- W_hh2 [512][128], gate-pair (unchanged)
    int s3 = s - 49152, mm = s3 >> 9, r = s3 & 511, gh = r >> 8, kc = (r >> 6) & 3; l = r & 63;
    int ul = (l & 15) >> 1, gp = l & 1;
    row = (gh*2+gp)*128 + mm*8 + ul; K = 128; k0 = kc*32 + (l>>4)*8; src = W_hh2;
  } else {                    // R1i <- W_ih1 [1024][256], gate-per-acc: col = l&15
    int s4 = s - 57344, mm = s4 >> 11, r = s4 & 2047, g = r >> 9, kc = (r >> 6) & 7; l = r & 63;
    row = g*256 + mm*16 + (l & 15); K = 256; k0 = kc*32 + (l>>4)*8; src = W_ih1;
  }
  const float* p = src + (size_t)row * K + k0;
  bf16x8 o;
  #pragma unroll
  for (int e = 0; e < 8; ++e) o[e] = f2bf(p[e]);
  *(bf16x8*)(wp + (size_t)s * 8) = o;
}

// 256 blocks x 512 threads, 1 block/CU (LDS-padded). 16 groups x 16 members,
// 256 rows/group. R8 skeleton (block-lockstep, coalesced exchange publish) +
// layer1 gate-per-accumulator packing (register-local gates1). Two barriers
// per iter — PROVEN necessary: they stagger exchange reads ahead of NT out
// stores (R14: reads after NT stores -> L2 victimized -> FETCH 141MB) and
// hide a0-load latency under gates2 (R13/R14: immediate drain exposes it).
__global__ __launch_bounds__(512, 2) void lstm_persist(
    const float* __restrict__ emb, const float* __restrict__ b_ih1,
    const float* __restrict__ b_hh1, const float* __restrict__ b_ih2,
    const float* __restrict__ b_hh2, char* __restrict__ ws,
    float* __restrict__ out) {
  extern __shared__ __align__(16) short ldsW[];
  char* ldsB = (char*)ldsW;
  const short* wp = (const short*)ws;
  unsigned* ctrl = (unsigned*)(ws + CTRL_B);
  __shared__ unsigned s_gm;
  const int tid = threadIdx.x, w = tid >> 6, l = tid & 63, l15 = l & 15, l4 = l >> 4;
  const int ul = l15 >> 1, gp = l15 & 1;

  // claim a (group, member) slot on this block's own XCD -> same-XCD groups
  if (tid == 0) {
    unsigned xcc;
    asm volatile("s_getreg_b32 %0, hwreg(HW_REG_XCC_ID)" : "=s"(xcc));
    xcc &= 7u;
    unsigned slot = atomicAdd(&ctrl[xcc * 32], 1u);
    s_gm = ((xcc * 2u + ((slot >> 4) & 1u)) << 8) | (slot & 15u);
  }
  __syncthreads();
  const int group = s_gm >> 8, member = s_gm & 255;

  // copy this member's weight slices into LDS (56KB: W_hh1 32KB | W_ih2 16KB | W_hh2 8KB)
  {
    const char* wpB = (const char*)wp;
    #pragma unroll
    for (int it = 0; it < 7; ++it) {
      int byte = (tid + it * 512) * 16;
      const char* src;
      if (byte < 32768)      src = wpB + (size_t)R1S * 2  + member * 32768 + byte;
      else if (byte < 49152) src = wpB + (size_t)R2AS * 2 + member * 16384 + (byte - 32768);
      else                   src = wpB + (size_t)R2BS * 2 + member * 8192  + (byte - 49152);
      *(f32x4*)(ldsB + byte) = *(const f32x4*)src;
    }
  }
  float b2[2];
  #pragma unroll
  for (int gh = 0; gh < 2; ++gh) {
    int rw = (gh*2+gp)*128 + member*8 + ul;
    b2[gh] = b_ih2[rw] + b_hh2[rw];
  }
  float b1[4];
  #pragma unroll
  for (int g = 0; g < 4; ++g) {
    int rw = g*256 + member*16 + l15;
    b1[g] = b_ih1[rw] + b_hh1[rw];
  }
  __syncthreads();   // LDS weights ready

  // x1 = emb @ W_ih1^T + b1 for rows [group*256 + w*32, +32), kept in registers
  const int grow0 = group * 256;
  const int rw0 = w * 32;
  f32x4 x1[2][4];
  #pragma unroll
  for (int m = 0; m < 2; ++m)
    #pragma unroll
    for (int g = 0; g < 4; ++g) x1[m][g] = splat4(b1[g]);
  #pragma unroll
  for (int kc = 0; kc < 8; ++kc) {
    bf16x8 af[2];
    #pragma unroll
    for (int m = 0; m < 2; ++m) {
      const float* ep = emb + (size_t)(grow0 + rw0 + m*16 + l15) * 256 + kc*32 + l4*8;
      f32x4 lo = *(const f32x4*)ep, hi = *(const f32x4*)(ep + 4);
      bf16x8 t8;
      #pragma unroll
      for (int e = 0; e < 4; ++e) { t8[e] = f2bf(lo[e]); t8[e+4] = f2bf(hi[e]); }
      af[m] = t8;
    }
    #pragma unroll
    for (int g = 0; g < 4; ++g) {
      bf16x8 bb = *(const bf16x8*)(wp + R1IS + (((size_t)member*4 + g)*8 + kc)*512 + l*8);
      x1[0][g] = __builtin_amdgcn_mfma_f32_16x16x32_bf16(af[0], bb, x1[0][g], 0, 0, 0);
      x1[1][g] = __builtin_amdgcn_mfma_f32_16x16x32_bf16(af[1], bb, x1[1][g], 0, 0, 0);
    }
  }

  bf16x8 a0[2][8], a1[2][4];
  const bf16x8 ZB = {0,0,0,0,0,0,0,0};
  #pragma unroll
  for (int m = 0; m < 2; ++m) {
    #pragma unroll
    for (int kc = 0; kc < 8; ++kc) a0[m][kc] = ZB;
    #pragma unroll
    for (int kc = 0; kc < 4; ++kc) a1[m][kc] = ZB;
  }
  float c0[2][4] = {};   // [m][r] — register-local layer1 gates
  float c1[2][2] = {};   // [m][rr]

  unsigned* flgA = &ctrl[512 + group * 64];        // 16 words, own 128B line
  unsigned* flgB = flgA + 32;                      // separate 128B line
  char* h0x = ws + H0X_B;
  char* h1x = ws + H1X_B;

  #pragma unroll 1
  for (int u = 0; u <= 128; ++u) {
    // ============ step 1: layer1(u), stage + coalesced publish h0(u) ============
    if (u < 128) {
      vm_drain_sched();    // a0 sc0-loads (and prev NT out) have landed
      f32x4 acc1[2][4];
      #pragma unroll
      for (int m = 0; m < 2; ++m)
        #pragma unroll
        for (int g = 0; g < 4; ++g) acc1[m][g] = x1[m][g];
      #pragma unroll
      for (int g = 0; g < 4; ++g)
        #pragma unroll
        for (int kc = 0; kc < 8; ++kc) {
          bf16x8 bb = *(const bf16x8*)(ldsW + (g*8 + kc)*512 + l*8);
          acc1[0][g] = __builtin_amdgcn_mfma_f32_16x16x32_bf16(a0[0][kc], bb, acc1[0][g], 0,0,0);
          acc1[1][g] = __builtin_amdgcn_mfma_f32_16x16x32_bf16(a0[1][kc], bb, acc1[1][g], 0,0,0);
        }
      // gates1: fully register-local (i,f,g,o live in this lane's 4 accumulators)
      #pragma unroll
      for (int m = 0; m < 2; ++m)
        #pragma unroll
        for (int r = 0; r < 4; ++r) {
          float iv = acc1[m][0][r], fv = acc1[m][1][r];
          float gv = acc1[m][2][r], ov = acc1[m][3][r];
          float c = sigm(fv) * c0[m][r] + sigm(iv) * tanh_f(gv);
          c0[m][r] = c;
          float h = sigm(ov) * tanh_f(c);
          int row = rw0 + m*16 + l4*4 + r;
          *(short*)(ldsB + H0S + row*32 + l15*2) = f2bf(h);
        }
      // coalesced publish: my wave's 32-row window = 1KB = one dwordx4 per lane
      {
        char* h0w = h0x + ((size_t)(u & 1) * 16 + group) * 131072;
        int prow = rw0 + (l >> 1);
        int off = prow*32 + (l & 1)*16;
        bf16x8 v = *(const bf16x8*)(ldsB + H0S + off);
        *(bf16x8*)(h0w + member*8192 + off) = v;
      }
      asm volatile("s_waitcnt vmcnt(0)" ::: "memory");   // h0 visible in L2
      __syncthreads();
      if (tid == 0)
        __hip_atomic_store(&flgA[member], (unsigned)(u + 1),
                           __ATOMIC_RELAXED, __HIP_MEMORY_SCOPE_AGENT);
    }
    // ============ step 2+3: waitB -> a1 load -> layer2(u-1) MFMA ============
    f32x4 acc2[2][2];
    if (u >= 1) {
      if (u >= 2) {   // peers published h1(u-2) one full iteration ago
        unsigned tgt = (unsigned)(u - 1); int z = 0;
        while (true) {
          unsigned v = __hip_atomic_load(&flgB[l15], __ATOMIC_RELAXED, __HIP_MEMORY_SCOPE_AGENT);
          if (__all((int)(v >= tgt))) break;
          __builtin_amdgcn_s_sleep(1);
          if (++z > (1 << 20)) break;   // escape hatch: fail visibly, never hang
        }
        __builtin_amdgcn_sched_barrier(0);
        const char* h1r = h1x + ((size_t)((u - 2) & 1) * 16 + group) * 65536;
        #pragma unroll
        for (int m = 0; m < 2; ++m)
          #pragma unroll
          for (int kc = 0; kc < 4; ++kc)
            ld_b128_sc0(&a1[m][kc], h1r + (kc*4 + l4)*4096 + (rw0 + m*16 + l15)*16);
        vm_drain_sched();
      }
      #pragma unroll
      for (int m = 0; m < 2; ++m)
        #pragma unroll
        for (int gh = 0; gh < 2; ++gh) acc2[m][gh] = splat4(b2[gh]);
      #pragma unroll
      for (int gh = 0; gh < 2; ++gh)
        #pragma unroll
        for (int kc = 0; kc < 8; ++kc) {
          bf16x8 bb = *(const bf16x8*)(ldsW + 16384 + (gh*8 + kc)*512 + l*8);
          acc2[0][gh] = __builtin_amdgcn_mfma_f32_16x16x32_bf16(a0[0][kc], bb, acc2[0][gh], 0,0,0);
          acc2[1][gh] = __builtin_amdgcn_mfma_f32_16x16x32_bf16(a0[1][kc], bb, acc2[1][gh], 0,0,0);
        }
      #pragma unroll
      for (int gh = 0; gh < 2; ++gh)
        #pragma unroll
        for (int kc = 0; kc < 4; ++kc) {
          bf16x8 bb = *(const bf16x8*)(ldsW + 24576 + (gh*4 + kc)*512 + l*8);
          acc2[0][gh] = __builtin_amdgcn_mfma_f32_16x16x32_bf16(a1[0][kc], bb, acc2[0][gh], 0,0,0);
          acc2[1][gh] = __builtin_amdgcn_mfma_f32_16x16x32_bf16(a1[1][kc], bb, acc2[1][gh], 0,0,0);
        }
    }
    // ============ step 4: waitA -> ISSUE a0 = h0(u) loads (hide under gates2) ====
    if (u < 128) {
      unsigned tgt = (unsigned)(u + 1); int z = 0;
      while (true) {
        unsigned v = __hip_atomic_load(&flgA[l15], __ATOMIC_RELAXED, __HIP_MEMORY_SCOPE_AGENT);
        if (__all((int)(v >= tgt))) break;
        __builtin_amdgcn_s_sleep(1);
        if (++z > (1 << 20)) break;
      }
      __builtin_amdgcn_sched_barrier(0);
      const char* h0r = h0x + ((size_t)(u & 1) * 16 + group) * 131072;
      #pragma unroll
      for (int m = 0; m < 2; ++m)
        #pragma unroll
        for (int kc = 0; kc < 8; ++kc)
          ld_b128_sc0(&a0[m][kc],
                      h0r + (kc*2 + (l4 >> 1))*8192 + (rw0 + m*16 + l15)*32 + (l4 & 1)*16);
      __builtin_amdgcn_sched_barrier(0);
      // NOT drained here: loads complete during gates2 below / at the sync.
    }
    // ============ step 5: gates2(t=u-1) -> stages; publish h1; out copy ========
    if (u >= 1) {
      const int t = u - 1;
      #pragma unroll
      for (int m = 0; m < 2; ++m) {
        f32x4 v0 = acc2[m][0], v1 = acc2[m][1];
        #pragma unroll
        for (int rr = 0; rr < 2; ++rr) {
          float s0 = gp ? v0[rr] : v0[2+rr];
          float s1 = gp ? v1[rr] : v1[2+rr];
          float p0 = __shfl_xor(s0, 1, 64);
          float p1 = __shfl_xor(s1, 1, 64);
          float o0 = gp ? v0[2+rr] : v0[rr];
          float o1 = gp ? v1[2+rr] : v1[rr];
          float iv = gp ? p0 : o0, fv = gp ? o0 : p0;
          float gv = gp ? p1 : o1, ov = gp ? o1 : p1;
          float c = sigm(fv) * c1[m][rr] + sigm(iv) * tanh_f(gv);
          c1[m][rr] = c;
          float h = sigm(ov) * tanh_f(c);
          int row = rw0 + m*16 + l4*4 + gp*2 + rr;
          *(short*)(ldsB + H1S + row*16 + ul*2) = f2bf(h);
          *(float*)(ldsB + OUTS + row*32 + ul*4) = h;
        }
      }
      if (u < 128) {
        // coalesced publish h1: my wave's 512B window = one dwordx2 per lane
        char* h1w = h1x + ((size_t)(t & 1) * 16 + group) * 65536;
        int prow = rw0 + (l >> 1);
        int off = prow*16 + (l & 1)*8;
        bf16x4 v = *(const bf16x4*)(ldsB + H1S + off);
        *(bf16x4*)(h1w + member*4096 + off) = v;
        asm volatile("s_waitcnt vmcnt(0)" ::: "memory");  // h1 in L2 (+a0 landed)
        __syncthreads();
        if (tid == 0)
          __hip_atomic_store(&flgB[member], (unsigned)u,
                             __ATOMIC_RELAXED, __HIP_MEMORY_SCOPE_AGENT);
      }
      // out(t): coalesced NT, 1KB window = one dwordx4 per lane (drained next iter)
      {
        int prow = rw0 + (l >> 1);
        f32x4 v = *(const f32x4*)(ldsB + OUTS + prow*32 + (l & 1)*16);
        float* op = out + (size_t)(grow0 + prow) * 16384 + (size_t)t*128 + member*8 + (l & 1)*4;
        __builtin_nontemporal_store(v, (f32x4*)op);
      }
    }
  }
}

extern "C" void kernel_launch(void* const* d_in, const int* in_sizes, int n_in,
                              void* d_out, int out_size, void* d_ws, size_t ws_size,
                              hipStream_t stream) {
  const float* emb   = (const float*)d_in[0];
  const float* W_ih1 = (const float*)d_in[1];
  const float* W_hh1 = (const float*)d_in[2];
  const float* b_ih1 = (const float*)d_in[3];
  const float* b_hh1 = (const float*)d_in[4];
  const float* W_ih2 = (const float*)d_in[5];
  const float* W_hh2 = (const float*)d_in[6];
  const float* b_ih2 = (const float*)d_in[7];
  const float* b_hh2 = (const float*)d_in[8];
  char* ws = (char*)d_ws;
  float* out = (float*)d_out;

  hipFuncSetAttribute((const void*)lstm_persist,
                      hipFuncAttributeMaxDynamicSharedMemorySize, 98304);
  pack_w<<<352, 256, 0, stream>>>(W_ih1, W_hh1, W_ih2, W_hh2, (short*)d_ws);
  lstm_persist<<<256, 512, 98304, stream>>>(emb, b_ih1, b_hh1, b_ih2, b_hh2, ws, out);
}